// Round 3
// baseline (13394.000 us; speedup 1.0000x reference)
//
#include <hip/hip_runtime.h>
#include <hip/hip_bf16.h>

// Geometry: x [1,16,128,128,16] fp32 NCDHW. C=16, D=128, H=128, W=16.
// Output: fp32, 4194304 elements (reference computes in float32 end-to-end).
constexpr int C  = 16;
constexpr int DD = 128;
constexpr int HH = 128;
constexpr int WW = 16;
constexpr int HW = HH * WW;       // 2048
constexpr int SP = DD * HW;       // 262144
constexpr int TOT = C * SP;       // 4194304

#define BN_EPS 1e-5f

// ---------------------------------------------------------------------------
// Direct conv + fused BN.  One thread per output element.
// Block 256 = 16(w) x 16(h); grid = 16(c_out) * 128(d) * 8(h-tile).
// Weights for this block's c_out staged in LDS (broadcast reads).
// ACCUM: out[i] += val.  bn_g==nullptr -> identity BN (1x1x1 channel mix).
// ---------------------------------------------------------------------------
template <int KD, int KH, int KW, bool ACCUM>
__global__ __launch_bounds__(256)
void conv_bn_kernel(const float* __restrict__ in, const float* __restrict__ wgt,
                    const float* __restrict__ bn_g, const float* __restrict__ bn_b,
                    const float* __restrict__ bn_m, const float* __restrict__ bn_v,
                    int layer, float* __restrict__ out)
{
    constexpr int PD = (KD - 1) / 2;
    constexpr int PH = (KH - 1) / 2;
    constexpr int PW = (KW - 1) / 2;
    constexpr int KHW = KD * KH * KW;
    constexpr int WSZ = C * KHW;

    __shared__ float lw[WSZ];

    const int bid = blockIdx.x;
    const int co  = bid >> 10;          // 1024 blocks per c_out (128 d * 8 ht)
    const int rem = bid & 1023;
    const int d   = rem >> 3;
    const int ht  = rem & 7;
    const int tid = threadIdx.x;
    const int w   = tid & 15;
    const int h   = ht * 16 + (tid >> 4);

    for (int i = tid; i < WSZ; i += 256) lw[i] = wgt[co * WSZ + i];
    __syncthreads();

    float scale = 1.0f, shift = 0.0f;
    if (bn_g) {
        const int bi = layer * C + co;
        const float g = bn_g[bi], b = bn_b[bi], m = bn_m[bi], v = bn_v[bi];
        scale = g / sqrtf(v + BN_EPS);
        shift = b - m * scale;
    }

    float acc = 0.0f;
    for (int ci = 0; ci < C; ++ci) {
        const float* __restrict__ xc = in + ci * SP;
        const float* __restrict__ wc = lw + ci * KHW;
        for (int kd = 0; kd < KD; ++kd) {
            const int dz = d + kd - PD;
            if ((unsigned)dz >= (unsigned)DD) continue;
            for (int kh = 0; kh < KH; ++kh) {
                const int hz = h + kh - PH;
                if ((unsigned)hz >= (unsigned)HH) continue;
                const float* __restrict__ row = xc + dz * HW + hz * WW;
                const float* __restrict__ wr  = wc + (kd * KH + kh) * KW;
#pragma unroll
                for (int kw = 0; kw < KW; ++kw) {
                    const int wz = w + kw - PW;
                    if ((unsigned)wz < (unsigned)WW)
                        acc = fmaf(row[wz], wr[kw], acc);
                }
            }
        }
    }

    const float val = acc * scale + shift;
    const int o = co * SP + d * HW + h * WW + w;
    if (ACCUM) out[o] += val;
    else       out[o] = val;
}

// ---------------------------------------------------------------------------
// Elementwise fused kernels (all fp32)
// ---------------------------------------------------------------------------
// t1 = relu(B1) stored to `t1` (d_out used as scratch); B1 += B0.
__global__ __launch_bounds__(256)
void t1_fuse_kernel(const float* __restrict__ B0, float* __restrict__ B1,
                    float* __restrict__ t1)
{
    const int i = blockIdx.x * 256 + threadIdx.x;
    const float pre = B1[i];
    t1[i] = fmaxf(pre, 0.0f);
    B1[i] = pre + B0[i];
}

__global__ __launch_bounds__(256)
void relu_inplace_kernel(float* __restrict__ a)
{
    const int i = blockIdx.x * 256 + threadIdx.x;
    a[i] = fmaxf(a[i], 0.0f);
}

// out = relu(acc)  (fp32 output!)
__global__ __launch_bounds__(256)
void final_kernel(const float* __restrict__ acc, float* __restrict__ o)
{
    const int i = blockIdx.x * 256 + threadIdx.x;
    o[i] = fmaxf(acc[i], 0.0f);
}

// ---------------------------------------------------------------------------
extern "C" void kernel_launch(void* const* d_in, const int* in_sizes, int n_in,
                              void* d_out, int out_size, void* d_ws, size_t ws_size,
                              hipStream_t stream)
{
    const float* x    = (const float*)d_in[0];
    const float* w1   = (const float*)d_in[1];
    const float* w2   = (const float*)d_in[2];
    const float* w3   = (const float*)d_in[3];
    const float* w4   = (const float*)d_in[4];
    const float* w5   = (const float*)d_in[5];
    const float* w6   = (const float*)d_in[6];
    const float* w7   = (const float*)d_in[7];
    const float* wch  = (const float*)d_in[8];
    const float* wr1  = (const float*)d_in[9];
    const float* wr2  = (const float*)d_in[10];
    const float* wr3  = (const float*)d_in[11];
    const float* bng  = (const float*)d_in[12];
    const float* bnb  = (const float*)d_in[13];
    const float* bnm  = (const float*)d_in[14];
    const float* bnv  = (const float*)d_in[15];
    float* out = (float*)d_out;            // fp32 output

    float* B0 = (float*)d_ws;     // x1, later x1 + y0+y1+y2+y3
    float* B1 = B0 + TOT;         // x2+x3+x4 -> +x1 -> +x5+x6+x7 -> xs
    float* T1 = out;              // t1 staged in d_out (fp32), dead before final

    const dim3 grid(16 * 128 * 8), blk(256);
    const dim3 egrid(TOT / 256);

    // B0 = x1 = cbn(x, w1, 0)
    conv_bn_kernel<3,3,1,false><<<grid, blk, 0, stream>>>(x,  w1, bng, bnb, bnm, bnv, 0, B0);
    // B1 = x2 + x3 + x4
    conv_bn_kernel<3,3,1,false><<<grid, blk, 0, stream>>>(B0, w2, bng, bnb, bnm, bnv, 1, B1);
    conv_bn_kernel<5,5,3,true ><<<grid, blk, 0, stream>>>(B0, w3, bng, bnb, bnm, bnv, 2, B1);
    conv_bn_kernel<7,7,5,true ><<<grid, blk, 0, stream>>>(B0, w4, bng, bnb, bnm, bnv, 3, B1);
    // T1 = t1 = relu(B1); B1 += B0  (B1 = x1+x2+x3+x4)
    t1_fuse_kernel<<<egrid, blk, 0, stream>>>(B0, B1, T1);
    // B1 += x5 + x6 + x7   (read T1, write B1 -> no aliasing)
    conv_bn_kernel<3,3,1,true ><<<grid, blk, 0, stream>>>(T1, w5, bng, bnb, bnm, bnv, 4, B1);
    conv_bn_kernel<5,5,3,true ><<<grid, blk, 0, stream>>>(T1, w6, bng, bnb, bnm, bnv, 5, B1);
    conv_bn_kernel<7,7,5,true ><<<grid, blk, 0, stream>>>(T1, w7, bng, bnb, bnm, bnv, 6, B1);
    // B1 = xs = relu(B1)
    relu_inplace_kernel<<<egrid, blk, 0, stream>>>(B1);
    // B0 += y0 = conv1x1(xs)   (no BN)
    conv_bn_kernel<1,1,1,true ><<<grid, blk, 0, stream>>>(B1, wch, nullptr, nullptr, nullptr, nullptr, 0, B0);
    // B0 += y1, y2, y3
    conv_bn_kernel<3,3,1,true ><<<grid, blk, 0, stream>>>(x, wr1, bng, bnb, bnm, bnv, 7, B0);
    conv_bn_kernel<5,5,3,true ><<<grid, blk, 0, stream>>>(x, wr2, bng, bnb, bnm, bnv, 8, B0);
    conv_bn_kernel<7,7,5,true ><<<grid, blk, 0, stream>>>(x, wr3, bng, bnb, bnm, bnv, 9, B0);
    // out = relu(B0)  -- overwrites T1 (dead)
    final_kernel<<<egrid, blk, 0, stream>>>(B0, out);

    (void)in_sizes; (void)n_in; (void)out_size; (void)ws_size;
}

// Round 4
// 3720.160 us; speedup vs baseline: 3.6004x; 3.6004x over previous
//
#include <hip/hip_runtime.h>
#include <hip/hip_bf16.h>

// Geometry: x [1,16,128,128,16] fp32 NCDHW. C=16, D=128, H=128, W=16.
// Output: fp32, 4194304 elements.
constexpr int C  = 16;
constexpr int DD = 128;
constexpr int HH = 128;
constexpr int WW = 16;
constexpr int HW = HH * WW;       // 2048
constexpr int SP = DD * HW;       // 262144
constexpr int TOT = C * SP;       // 4194304

#define BN_EPS 1e-5f

// ---------------------------------------------------------------------------
// Register-row direct conv + fused BN.
// Each thread computes a full W=16 output row (16 accumulator VGPRs) for one
// (co, d, h). Per (ci,kd,kh) the 16-float input row is loaded ONCE (4x
// dwordx4) and all KW taps hit it as statically-shifted FMAs (SAME-pad zeros
// are compile-time skipped). Load:FMA ratio ~1:25 for the 7x7x5 conv.
// Block 256 = 2(d) x 128(h). Grid = 16(co) * 64(d-pair).
// Weights for this co staged in LDS; reads are block-uniform broadcasts.
// ---------------------------------------------------------------------------
template <int KD, int KH, int KW, bool ACCUM>
__global__ __launch_bounds__(256)
void conv_bn_row_kernel(const float* __restrict__ in, const float* __restrict__ wgt,
                        const float* __restrict__ bn_g, const float* __restrict__ bn_b,
                        const float* __restrict__ bn_m, const float* __restrict__ bn_v,
                        int layer, float* __restrict__ out)
{
    constexpr int PD = (KD - 1) / 2;
    constexpr int PH = (KH - 1) / 2;
    constexpr int PW = (KW - 1) / 2;
    constexpr int KHW = KD * KH * KW;
    constexpr int WSZ = C * KHW;

    __shared__ float lw[WSZ];

    const int bid = blockIdx.x;
    const int co  = bid >> 6;           // 64 blocks per co
    const int dp  = bid & 63;
    const int tid = threadIdx.x;
    const int d   = dp * 2 + (tid >> 7);
    const int h   = tid & 127;

    for (int i = tid; i < WSZ; i += 256) lw[i] = wgt[co * WSZ + i];
    __syncthreads();

    float scale = 1.0f, shift = 0.0f;
    if (bn_g) {
        const int bi = layer * C + co;
        const float g = bn_g[bi], b = bn_b[bi], m = bn_m[bi], v = bn_v[bi];
        scale = g / sqrtf(v + BN_EPS);
        shift = b - m * scale;
    }

    float acc[16];
#pragma unroll
    for (int w = 0; w < 16; ++w) acc[w] = 0.0f;

    for (int ci = 0; ci < C; ++ci) {
        const float* __restrict__ xc = in + ci * SP;
        const float* __restrict__ wc = lw + ci * KHW;
        for (int kd = 0; kd < KD; ++kd) {
            const int dz = d + kd - PD;
            if ((unsigned)dz >= (unsigned)DD) continue;   // block-uniform
            const float* __restrict__ xd = xc + dz * HW;
            const float* __restrict__ wd = wc + kd * KH * KW;
            for (int kh = 0; kh < KH; ++kh) {
                const int hz = h + kh - PH;
                if ((unsigned)hz >= (unsigned)HH) continue;  // edge threads only
                const float4* __restrict__ rp = (const float4*)(xd + hz * WW);
                const float4 v0 = rp[0], v1 = rp[1], v2 = rp[2], v3 = rp[3];
                alignas(16) float r[16];
                *reinterpret_cast<float4*>(&r[0])  = v0;
                *reinterpret_cast<float4*>(&r[4])  = v1;
                *reinterpret_cast<float4*>(&r[8])  = v2;
                *reinterpret_cast<float4*>(&r[12]) = v3;
                const float* __restrict__ wr = wd + kh * KW;
#pragma unroll
                for (int kw = 0; kw < KW; ++kw) {
                    const float wt = wr[kw];   // block-uniform broadcast
#pragma unroll
                    for (int w = 0; w < 16; ++w) {
                        constexpr int dummy = 0; (void)dummy;
                        const int iw = w + kw - PW;
                        if (iw >= 0 && iw < 16)            // compile-time pruned
                            acc[w] = fmaf(r[iw], wt, acc[w]);
                    }
                }
            }
        }
    }

    float* __restrict__ op = out + co * SP + d * HW + h * WW;
    float4* __restrict__ ov = (float4*)op;
    float4 res[4];
#pragma unroll
    for (int q = 0; q < 4; ++q) {
        res[q].x = acc[q*4+0] * scale + shift;
        res[q].y = acc[q*4+1] * scale + shift;
        res[q].z = acc[q*4+2] * scale + shift;
        res[q].w = acc[q*4+3] * scale + shift;
    }
    if (ACCUM) {
        const float4 o0 = ov[0], o1 = ov[1], o2 = ov[2], o3 = ov[3];
        res[0].x += o0.x; res[0].y += o0.y; res[0].z += o0.z; res[0].w += o0.w;
        res[1].x += o1.x; res[1].y += o1.y; res[1].z += o1.z; res[1].w += o1.w;
        res[2].x += o2.x; res[2].y += o2.y; res[2].z += o2.z; res[2].w += o2.w;
        res[3].x += o3.x; res[3].y += o3.y; res[3].z += o3.z; res[3].w += o3.w;
    }
#pragma unroll
    for (int q = 0; q < 4; ++q) ov[q] = res[q];
}

// ---------------------------------------------------------------------------
// Elementwise fused kernels (float4-vectorized)
// ---------------------------------------------------------------------------
__device__ __forceinline__ float4 relu4(float4 a)
{
    return make_float4(fmaxf(a.x, 0.f), fmaxf(a.y, 0.f), fmaxf(a.z, 0.f), fmaxf(a.w, 0.f));
}
__device__ __forceinline__ float4 add4(float4 a, float4 b)
{
    return make_float4(a.x + b.x, a.y + b.y, a.z + b.z, a.w + b.w);
}

// t1 = relu(B1); B1 += B0
__global__ __launch_bounds__(256)
void t1_fuse_kernel(const float4* __restrict__ B0, float4* __restrict__ B1,
                    float4* __restrict__ t1)
{
    const int i = blockIdx.x * 256 + threadIdx.x;
    const float4 pre = B1[i];
    t1[i] = relu4(pre);
    B1[i] = add4(pre, B0[i]);
}

__global__ __launch_bounds__(256)
void relu_inplace_kernel(float4* __restrict__ a)
{
    const int i = blockIdx.x * 256 + threadIdx.x;
    a[i] = relu4(a[i]);
}

__global__ __launch_bounds__(256)
void final_kernel(const float4* __restrict__ acc, float4* __restrict__ o)
{
    const int i = blockIdx.x * 256 + threadIdx.x;
    o[i] = relu4(acc[i]);
}

// ---------------------------------------------------------------------------
extern "C" void kernel_launch(void* const* d_in, const int* in_sizes, int n_in,
                              void* d_out, int out_size, void* d_ws, size_t ws_size,
                              hipStream_t stream)
{
    const float* x    = (const float*)d_in[0];
    const float* w1   = (const float*)d_in[1];
    const float* w2   = (const float*)d_in[2];
    const float* w3   = (const float*)d_in[3];
    const float* w4   = (const float*)d_in[4];
    const float* w5   = (const float*)d_in[5];
    const float* w6   = (const float*)d_in[6];
    const float* w7   = (const float*)d_in[7];
    const float* wch  = (const float*)d_in[8];
    const float* wr1  = (const float*)d_in[9];
    const float* wr2  = (const float*)d_in[10];
    const float* wr3  = (const float*)d_in[11];
    const float* bng  = (const float*)d_in[12];
    const float* bnb  = (const float*)d_in[13];
    const float* bnm  = (const float*)d_in[14];
    const float* bnv  = (const float*)d_in[15];
    float* out = (float*)d_out;            // fp32 output

    float* B0 = (float*)d_ws;     // x1, later x1 + y0+y1+y2+y3
    float* B1 = B0 + TOT;         // x2+x3+x4 -> +x1 -> +x5+x6+x7 -> xs
    float* T1 = out;              // t1 staged in d_out (dead before final write)

    const dim3 grid(16 * 64), blk(256);
    const dim3 egrid(TOT / 1024);          // float4 elementwise

    // B0 = x1 = cbn(x, w1, 0)
    conv_bn_row_kernel<3,3,1,false><<<grid, blk, 0, stream>>>(x,  w1, bng, bnb, bnm, bnv, 0, B0);
    // B1 = x2 + x3 + x4
    conv_bn_row_kernel<3,3,1,false><<<grid, blk, 0, stream>>>(B0, w2, bng, bnb, bnm, bnv, 1, B1);
    conv_bn_row_kernel<5,5,3,true ><<<grid, blk, 0, stream>>>(B0, w3, bng, bnb, bnm, bnv, 2, B1);
    conv_bn_row_kernel<7,7,5,true ><<<grid, blk, 0, stream>>>(B0, w4, bng, bnb, bnm, bnv, 3, B1);
    // T1 = relu(B1); B1 += B0
    t1_fuse_kernel<<<egrid, blk, 0, stream>>>((const float4*)B0, (float4*)B1, (float4*)T1);
    // B1 += x5 + x6 + x7
    conv_bn_row_kernel<3,3,1,true ><<<grid, blk, 0, stream>>>(T1, w5, bng, bnb, bnm, bnv, 4, B1);
    conv_bn_row_kernel<5,5,3,true ><<<grid, blk, 0, stream>>>(T1, w6, bng, bnb, bnm, bnv, 5, B1);
    conv_bn_row_kernel<7,7,5,true ><<<grid, blk, 0, stream>>>(T1, w7, bng, bnb, bnm, bnv, 6, B1);
    // B1 = xs = relu(B1)
    relu_inplace_kernel<<<egrid, blk, 0, stream>>>((float4*)B1);
    // B0 += y0 = conv1x1(xs)
    conv_bn_row_kernel<1,1,1,true ><<<grid, blk, 0, stream>>>(B1, wch, nullptr, nullptr, nullptr, nullptr, 0, B0);
    // B0 += y1, y2, y3
    conv_bn_row_kernel<3,3,1,true ><<<grid, blk, 0, stream>>>(x, wr1, bng, bnb, bnm, bnv, 7, B0);
    conv_bn_row_kernel<5,5,3,true ><<<grid, blk, 0, stream>>>(x, wr2, bng, bnb, bnm, bnv, 8, B0);
    conv_bn_row_kernel<7,7,5,true ><<<grid, blk, 0, stream>>>(x, wr3, bng, bnb, bnm, bnv, 9, B0);
    // out = relu(B0)  (overwrites T1, which is dead)
    final_kernel<<<egrid, blk, 0, stream>>>((const float4*)B0, (float4*)out);

    (void)in_sizes; (void)n_in; (void)out_size; (void)ws_size;
}

// Round 5
// 435.411 us; speedup vs baseline: 30.7617x; 8.5440x over previous
//
#include <hip/hip_runtime.h>
#include <hip/hip_bf16.h>

typedef __attribute__((ext_vector_type(8))) short short8;   // 8 bf16 = 4 VGPRs
typedef __attribute__((ext_vector_type(4))) float f32x4;

constexpr int C  = 16;
constexpr int DD = 128, HH = 128, WW = 16;
constexpr int HW = HH * WW;        // 2048
constexpr int SP = DD * HW;        // 262144
constexpr int TOT = C * SP;        // 4194304

// Padded bf16 activation layout: [dp=134][hp=134][wp=20][ci=16]
// dp = d+3, hp = h+3, wp = w+2 (pads zeroed). Shared by ALL convs.
constexpr int WP_ = 20, HP_ = 134, DP_ = 134;
constexpr int ROWE   = WP_ * C;        // 320 elems per (dp,hp) row
constexpr int PLANEE = HP_ * ROWE;     // 42880
constexpr int PADE   = DP_ * PLANEE;   // 5,745,920 elems (11.49 MB bf16)

// ---------------------------------------------------------------------------
// MFMA implicit-GEMM conv + fused BN.
// One MFMA = 16co x 16w for one (d,h) row, K=32 = 2 taps x 16 ci.
// Block 256 = 4 waves; wave handles 4 consecutive h rows; grid = 128d x 8hb.
// B-frag: lane l reads bf16x8 at [dz(tap)][hz(tap)][l&15 + kw(tap)][ci-half].
// A-frag: pre-packed per tap-pair, lane-indexed (coalesced 1KB loads).
// Epilogue: BN scale/shift, optional accumulate into F [d][h][w][co] fp32.
// ---------------------------------------------------------------------------
template <int KD, int KH, int KW, int NTAPS, bool ACCUM, bool BN>
__global__ __launch_bounds__(256, 4)
void conv_mfma(const short* __restrict__ xp, const short* __restrict__ wpk,
               const float* __restrict__ bn_g, const float* __restrict__ bn_b,
               const float* __restrict__ bn_m, const float* __restrict__ bn_v,
               int layer, float* __restrict__ F)
{
    constexpr int PD = (KD - 1) / 2, PH = (KH - 1) / 2, PW = (KW - 1) / 2;
    constexpr int NP = (NTAPS + 1) / 2;

    const int b    = blockIdx.x;
    const int d    = b >> 3, hb = b & 7;
    const int tid  = threadIdx.x;
    const int wid  = tid >> 6, lane = tid & 63;
    const int h0   = hb * 16 + wid * 4;

    const int l15  = lane & 15;            // w (B/N), co (A/M)
    const int cih  = (lane >> 4) & 1;      // ci half
    const int tsel = lane >> 5;            // which tap of the pair
    const unsigned laneoff = (unsigned)(l15 * 32 + cih * 16);   // bytes

    unsigned off_r[4];
#pragma unroll
    for (int r = 0; r < 4; ++r) {
        const int h = h0 + r;
        off_r[r] = (unsigned)((((d + (3 - PD)) * HP_ + (h + (3 - PH))) * ROWE
                               + (2 - PW) * C) * 2) + laneoff;
    }

    const char* xb = (const char*)xp;
    const char* wb = (const char*)wpk;

    f32x4 acc[4] = {};
#pragma unroll 2
    for (int p = 0; p < NP; ++p) {
        const int ta = 2 * p;
        const int tb = (2 * p + 1 < NTAPS) ? 2 * p + 1 : NTAPS - 1;
        const int kda = ta / (KH * KW), ra = ta % (KH * KW);
        const int kha = ra / KW,        kwa = ra % KW;
        const int kdb = tb / (KH * KW), rb = tb % (KH * KW);
        const int khb = rb / KW,        kwb = rb % KW;
        const unsigned toa = (unsigned)((kda * PLANEE + kha * ROWE + kwa * C) * 2);
        const unsigned tob = (unsigned)((kdb * PLANEE + khb * ROWE + kwb * C) * 2);
        const unsigned ts  = tsel ? tob : toa;

        const short8 a = *(const short8*)(wb + (unsigned)(p * 1024 + lane * 16));
#pragma unroll
        for (int r = 0; r < 4; ++r) {
            const short8 bf = *(const short8*)(xb + (off_r[r] + ts));
            acc[r] = __builtin_amdgcn_mfma_f32_16x16x32_bf16(a, bf, acc[r], 0, 0, 0);
        }
    }

    // Epilogue: BN + (accumulate) + store.  Lane l holds co = (l>>4)*4+j, w = l&15.
    float sc[4], sh[4];
    if (BN) {
        const int cb = (lane >> 4) * 4;
        const f32x4 g  = *(const f32x4*)(bn_g + layer * C + cb);
        const f32x4 be = *(const f32x4*)(bn_b + layer * C + cb);
        const f32x4 m  = *(const f32x4*)(bn_m + layer * C + cb);
        const f32x4 v  = *(const f32x4*)(bn_v + layer * C + cb);
#pragma unroll
        for (int j = 0; j < 4; ++j) { sc[j] = g[j] / sqrtf(v[j] + 1e-5f); sh[j] = be[j] - m[j] * sc[j]; }
    } else {
#pragma unroll
        for (int j = 0; j < 4; ++j) { sc[j] = 1.f; sh[j] = 0.f; }
    }
#pragma unroll
    for (int r = 0; r < 4; ++r) {
        const int h = h0 + r;
        float* dst = F + (unsigned)(((d * HH + h) * WW + l15) * C + (lane >> 4) * 4);
        f32x4 val;
#pragma unroll
        for (int j = 0; j < 4; ++j) val[j] = acc[r][j] * sc[j] + sh[j];
        if (ACCUM) {
            const f32x4 old = *(const f32x4*)dst;
#pragma unroll
            for (int j = 0; j < 4; ++j) val[j] += old[j];
        }
        *(f32x4*)dst = val;
    }
}

// ---------------------------------------------------------------------------
// x (fp32 [ci][d][h][w]) -> padded bf16 [dp][hp][wp][ci]
// ---------------------------------------------------------------------------
__global__ __launch_bounds__(256)
void pack_x(const float* __restrict__ x, short* __restrict__ xp)
{
    const int b  = blockIdx.x;            // dp*134 + hp
    const int dp = b / HP_, hp = b % HP_;
    const int t  = threadIdx.x;
    const int d  = dp - 3, h = hp - 3;
    const bool inr = ((unsigned)d < (unsigned)DD) && ((unsigned)h < (unsigned)HH);
    short* row = xp + (unsigned)(dp * PLANEE + hp * ROWE);

    const int w = t & 15, ci = t >> 4;
    float v = 0.f;
    if (inr) v = x[ci * SP + d * HW + h * WW + w];
    __hip_bfloat16 hv = __float2bfloat16(v);
    row[(w + 2) * C + ci] = *(short*)&hv;
    if (t < 64) {                          // zero the wp pads {0,1,18,19}
        const int pi = t >> 4;
        const int wp = (pi < 2) ? pi : (16 + pi);
        row[wp * C + (t & 15)] = 0;
    }
}

// ---------------------------------------------------------------------------
// F (fp32 [d][h][w][ci]) -> padded bf16 (optional relu); optional S += A2.
// ---------------------------------------------------------------------------
template <bool RELU, bool ADD>
__global__ __launch_bounds__(256)
void pack_f(float* __restrict__ S, const float* __restrict__ A2,
            short* __restrict__ P)
{
    const int b  = blockIdx.x;
    const int dp = b / HP_, hp = b % HP_;
    const int t  = threadIdx.x;
    const int d  = dp - 3, h = hp - 3;
    const bool inr = ((unsigned)d < (unsigned)DD) && ((unsigned)h < (unsigned)HH);
    short* row = P + (unsigned)(dp * PLANEE + hp * ROWE);

    const int ci = t & 15, w = t >> 4;
    float pv = 0.f;
    if (inr) {
        const unsigned idx = (unsigned)(((d * HH + h) * WW + w) * C + ci);
        const float v = S[idx];
        pv = RELU ? fmaxf(v, 0.f) : v;
        if (ADD) S[idx] = v + A2[idx];
    }
    __hip_bfloat16 hv = __float2bfloat16(pv);
    row[(w + 2) * C + ci] = *(short*)&hv;
    if (t < 64) {
        const int pi = t >> 4;
        const int wp = (pi < 2) ? pi : (16 + pi);
        row[wp * C + (t & 15)] = 0;
    }
}

// ---------------------------------------------------------------------------
// Weight pack: OIDHW fp32 -> per-tap-pair lane-indexed bf16 A-fragments.
// Element (pair p, lane l, j): co=l&15, tap=2p+(l>>5), ci=((l>>4)&1)*8+j.
// ---------------------------------------------------------------------------
__global__ __launch_bounds__(256)
void pack_w(const float* __restrict__ src, short* __restrict__ dst,
            int KHW, int NTAPS)
{
    const int p  = blockIdx.x;
    const int t  = threadIdx.x;
    const int l  = t >> 2, jj = t & 3;
    const int co = l & 15, cih = (l >> 4) & 1, tp = l >> 5;
    const int tap = 2 * p + tp;
    unsigned out = 0;
#pragma unroll
    for (int s = 0; s < 2; ++s) {
        const int j  = jj * 2 + s;
        const int ci = cih * 8 + j;
        const float v = (tap < NTAPS) ? src[(co * C + ci) * KHW + tap] : 0.f;
        __hip_bfloat16 hv = __float2bfloat16(v);
        out |= ((unsigned)*(unsigned short*)&hv) << (16 * s);
    }
    ((unsigned*)dst)[p * 256 + l * 4 + jj] = out;
}

// ---------------------------------------------------------------------------
// Final: out[co][d][h][w] = relu(F1[d][h][w][co])  (LDS 16x16 transpose)
// ---------------------------------------------------------------------------
__global__ __launch_bounds__(256)
void final_tr(const float* __restrict__ F, float* __restrict__ out)
{
    __shared__ float lds[16 * 17];
    const int b = blockIdx.x;
    const int d = b >> 3, hb = b & 7;
    const int t = threadIdx.x;
    for (int hh = 0; hh < 16; ++hh) {
        const int h = hb * 16 + hh;
        {
            const int ci = t & 15, w = t >> 4;
            const float v = F[(unsigned)(((d * HH + h) * WW + w) * C + ci)];
            lds[w * 17 + ci] = fmaxf(v, 0.f);
        }
        __syncthreads();
        {
            const int w = t & 15, co = t >> 4;
            out[(unsigned)(co * SP + d * HW + h * WW + w)] = lds[w * 17 + co];
        }
        __syncthreads();
    }
}

// ---------------------------------------------------------------------------
extern "C" void kernel_launch(void* const* d_in, const int* in_sizes, int n_in,
                              void* d_out, int out_size, void* d_ws, size_t ws_size,
                              hipStream_t stream)
{
    const float* x    = (const float*)d_in[0];
    const float* wsrc[11] = {
        (const float*)d_in[1],  (const float*)d_in[2],  (const float*)d_in[3],
        (const float*)d_in[4],  (const float*)d_in[5],  (const float*)d_in[6],
        (const float*)d_in[7],  (const float*)d_in[8],  (const float*)d_in[9],
        (const float*)d_in[10], (const float*)d_in[11] };
    const float* bng  = (const float*)d_in[12];
    const float* bnb  = (const float*)d_in[13];
    const float* bnm  = (const float*)d_in[14];
    const float* bnv  = (const float*)d_in[15];

    // Workspace: xp | P2 (rotating x1p/t1p/xsp) | F1 fp32 | packed weights
    short* XP  = (short*)d_ws;
    short* P2  = XP + PADE;
    float* F1  = (float*)(P2 + PADE);
    short* WPK = (short*)(F1 + TOT);
    float* F2  = (float*)d_out;            // fp32 scratch; overwritten at the end

    // conv metadata: {KHW, NTAPS} per weight, NP = ceil(NTAPS/2)
    const int khw[11]   = {9, 9, 75, 245, 9, 75, 245, 1, 9, 75, 245};
    const int np[11]    = {5, 5, 38, 123, 5, 38, 123, 1, 5, 38, 123};
    int  woff[11]; { int o = 0; for (int i = 0; i < 11; ++i) { woff[i] = o; o += np[i] * 512; } }

    const dim3 blk(256);
    const dim3 pgrid(DP_ * HP_);           // 17956
    const dim3 cgrid(DD * 8);              // 1024

    for (int i = 0; i < 11; ++i)
        pack_w<<<dim3(np[i]), blk, 0, stream>>>(wsrc[i], WPK + woff[i], khw[i], khw[i]);

    pack_x<<<pgrid, blk, 0, stream>>>(x, XP);

    // x1 = cbn(x, w1, 0) -> F1
    conv_mfma<3,3,1,9,false,true><<<cgrid, blk, 0, stream>>>(XP, WPK + woff[0], bng, bnb, bnm, bnv, 0, F1);
    // x1p
    pack_f<false,false><<<pgrid, blk, 0, stream>>>(F1, nullptr, P2);
    // F2 = x2 + x3 + x4
    conv_mfma<3,3,1,9,false,true><<<cgrid, blk, 0, stream>>>(P2, WPK + woff[1], bng, bnb, bnm, bnv, 1, F2);
    conv_mfma<5,5,3,75,true,true><<<cgrid, blk, 0, stream>>>(P2, WPK + woff[2], bng, bnb, bnm, bnv, 2, F2);
    conv_mfma<7,7,5,245,true,true><<<cgrid, blk, 0, stream>>>(P2, WPK + woff[3], bng, bnb, bnm, bnv, 3, F2);
    // t1p = relu(F2); F2 += F1  (= x1+x2+x3+x4)
    pack_f<true,true><<<pgrid, blk, 0, stream>>>(F2, F1, P2);
    // F2 += x5 + x6 + x7
    conv_mfma<3,3,1,9,true,true><<<cgrid, blk, 0, stream>>>(P2, WPK + woff[4], bng, bnb, bnm, bnv, 4, F2);
    conv_mfma<5,5,3,75,true,true><<<cgrid, blk, 0, stream>>>(P2, WPK + woff[5], bng, bnb, bnm, bnv, 5, F2);
    conv_mfma<7,7,5,245,true,true><<<cgrid, blk, 0, stream>>>(P2, WPK + woff[6], bng, bnb, bnm, bnv, 6, F2);
    // xsp = relu(F2)
    pack_f<true,false><<<pgrid, blk, 0, stream>>>(F2, nullptr, P2);
    // F1 += y0 (1x1x1, no BN)
    conv_mfma<1,1,1,1,true,false><<<cgrid, blk, 0, stream>>>(P2, WPK + woff[7], bng, bnb, bnm, bnv, 0, F1);
    // F1 += y1, y2, y3
    conv_mfma<3,3,1,9,true,true><<<cgrid, blk, 0, stream>>>(XP, WPK + woff[8], bng, bnb, bnm, bnv, 7, F1);
    conv_mfma<5,5,3,75,true,true><<<cgrid, blk, 0, stream>>>(XP, WPK + woff[9], bng, bnb, bnm, bnv, 8, F1);
    conv_mfma<7,7,5,245,true,true><<<cgrid, blk, 0, stream>>>(XP, WPK + woff[10], bng, bnb, bnm, bnv, 9, F1);
    // out = relu(F1), transposed to [co][d][h][w]
    final_tr<<<cgrid, blk, 0, stream>>>(F1, (float*)d_out);

    (void)in_sizes; (void)n_in; (void)out_size; (void)ws_size;
}

// Round 6
// 357.864 us; speedup vs baseline: 37.4276x; 1.2167x over previous
//
#include <hip/hip_runtime.h>
#include <hip/hip_bf16.h>

typedef __attribute__((ext_vector_type(8))) short short8;   // 8 bf16 = 4 VGPRs
typedef __attribute__((ext_vector_type(4))) float f32x4;

constexpr int C  = 16;
constexpr int DD = 128, HH = 128, WW = 16;
constexpr int HW = HH * WW;        // 2048
constexpr int SP = DD * HW;        // 262144
constexpr int TOT = C * SP;        // 4194304

// Padded bf16 activation layout: [dp=134][hp=134][wp=20][ci=16]
// dp = d+3, hp = h+3, wp = w+2 (pads zeroed). Shared by ALL convs.
constexpr int WP_ = 20, HP_ = 134, DP_ = 134;
constexpr int ROWE   = WP_ * C;        // 320 elems per (dp,hp) row
constexpr int PLANEE = HP_ * ROWE;     // 42880
constexpr int PADE   = DP_ * PLANEE;   // 5,745,920 elems (11.49 MB bf16)

// ---------------------------------------------------------------------------
// Tiled MFMA implicit-GEMM conv + fused BN (for the 5x5x3 / 7x7x5 convs).
// Wave owns a TD=2 x TH=8 tile of output rows: acc[2][8] (64 VGPR).
// Loop kwp (kw-pairs, K=32 = 2 kw-taps x 16 ci), then dz; per dz the 14-row
// B halo is loaded ONCE into registers and all valid (kd,kh) taps are applied
// from registers: ~0.27 loads/MFMA instead of 1.25.
// Block = 4 waves = 2d x 32h. Grid = (128/2) x (128/32) = 256 blocks.
// ---------------------------------------------------------------------------
template <int KD, int KH, int KW, bool ACCUM, bool BN>
__global__ __launch_bounds__(256)
void conv_mfma_tile(const short* __restrict__ xp, const short* __restrict__ wpk,
                    const float* __restrict__ bn_g, const float* __restrict__ bn_b,
                    const float* __restrict__ bn_m, const float* __restrict__ bn_v,
                    int layer, float* __restrict__ F)
{
    constexpr int PD = (KD - 1) / 2, PH = (KH - 1) / 2, PW = (KW - 1) / 2;
    constexpr int KWP = (KW + 1) / 2;
    constexpr int TD = 2, TH = 8;
    constexpr int NU = TD + KD - 1;    // dz planes swept
    constexpr int NB = TH + KH - 1;    // B halo rows per dz

    const int b    = blockIdx.x;
    const int dblk = b >> 2, hb = b & 3;
    const int tid  = threadIdx.x;
    const int wid  = tid >> 6, lane = tid & 63;
    const int d0   = dblk * TD;
    const int h0   = hb * 32 + wid * TH;

    const int l15  = lane & 15;
    const int cih  = (lane >> 4) & 1;
    const int tsel = lane >> 5;

    const char* xb = (const char*)xp;
    const char* wb = (const char*)wpk;

    f32x4 acc[TD][TH] = {};

#pragma unroll 1
    for (int kwp = 0; kwp < KWP; ++kwp) {
        const int kwa = 2 * kwp;
        const int kwb = (2 * kwp + 1 < KW) ? 2 * kwp + 1 : KW - 1;  // pad: A=0
        const unsigned laneoff =
            (unsigned)((l15 + (tsel ? kwb : kwa) + (2 - PW)) * 32 + cih * 16);

#pragma unroll 1
        for (int u = 0; u < NU; ++u) {
            // dz = d0 - PD + u ; dp = dz + 3 = d0 + u + (3-PD)
            const unsigned rowbase =
                (unsigned)((((d0 + u + (3 - PD)) * HP_ + (h0 + (3 - PH))) * ROWE) * 2)
                + laneoff;
            short8 Bf[NB];
#pragma unroll
            for (int rB = 0; rB < NB; ++rB)
                Bf[rB] = *(const short8*)(xb + rowbase + (unsigned)(rB * ROWE * 2));

#pragma unroll
            for (int ad = 0; ad < TD; ++ad) {
                const int kd = u - ad;
                if (kd < 0 || kd >= KD) continue;       // wave-uniform
#pragma unroll
                for (int kh = 0; kh < KH; ++kh) {
                    const short8 a = *(const short8*)(
                        wb + (unsigned)((((kd * KH + kh) * KWP) + kwp) * 1024 + lane * 16));
#pragma unroll
                    for (int r = 0; r < TH; ++r)
                        acc[ad][r] = __builtin_amdgcn_mfma_f32_16x16x32_bf16(
                            a, Bf[r + kh], acc[ad][r], 0, 0, 0);
                }
            }
        }
    }

    // Epilogue: BN + (accumulate) + store.  Lane holds co=(lane>>4)*4+j, w=l15.
    float sc[4], sh[4];
    if (BN) {
        const int cb = (lane >> 4) * 4;
        const f32x4 g  = *(const f32x4*)(bn_g + layer * C + cb);
        const f32x4 be = *(const f32x4*)(bn_b + layer * C + cb);
        const f32x4 m  = *(const f32x4*)(bn_m + layer * C + cb);
        const f32x4 v  = *(const f32x4*)(bn_v + layer * C + cb);
#pragma unroll
        for (int j = 0; j < 4; ++j) { sc[j] = g[j] / sqrtf(v[j] + 1e-5f); sh[j] = be[j] - m[j] * sc[j]; }
    } else {
#pragma unroll
        for (int j = 0; j < 4; ++j) { sc[j] = 1.f; sh[j] = 0.f; }
    }
#pragma unroll
    for (int ad = 0; ad < TD; ++ad) {
#pragma unroll
        for (int r = 0; r < TH; ++r) {
            const int d = d0 + ad, h = h0 + r;
            float* dst = F + (unsigned)(((d * HH + h) * WW + l15) * C + (lane >> 4) * 4);
            f32x4 val;
#pragma unroll
            for (int j = 0; j < 4; ++j) val[j] = acc[ad][r][j] * sc[j] + sh[j];
            if (ACCUM) {
                const f32x4 old = *(const f32x4*)dst;
#pragma unroll
                for (int j = 0; j < 4; ++j) val[j] += old[j];
            }
            *(f32x4*)dst = val;
        }
    }
}

// ---------------------------------------------------------------------------
// Round-5 kernel, kept for the small convs (3x3x1 taps=9, 1x1x1 taps=1).
// ---------------------------------------------------------------------------
template <int KD, int KH, int KW, int NTAPS, bool ACCUM, bool BN>
__global__ __launch_bounds__(256, 4)
void conv_mfma(const short* __restrict__ xp, const short* __restrict__ wpk,
               const float* __restrict__ bn_g, const float* __restrict__ bn_b,
               const float* __restrict__ bn_m, const float* __restrict__ bn_v,
               int layer, float* __restrict__ F)
{
    constexpr int PD = (KD - 1) / 2, PH = (KH - 1) / 2, PW = (KW - 1) / 2;
    constexpr int NP = (NTAPS + 1) / 2;

    const int b    = blockIdx.x;
    const int d    = b >> 3, hb = b & 7;
    const int tid  = threadIdx.x;
    const int wid  = tid >> 6, lane = tid & 63;
    const int h0   = hb * 16 + wid * 4;

    const int l15  = lane & 15;
    const int cih  = (lane >> 4) & 1;
    const int tsel = lane >> 5;
    const unsigned laneoff = (unsigned)(l15 * 32 + cih * 16);

    unsigned off_r[4];
#pragma unroll
    for (int r = 0; r < 4; ++r) {
        const int h = h0 + r;
        off_r[r] = (unsigned)((((d + (3 - PD)) * HP_ + (h + (3 - PH))) * ROWE
                               + (2 - PW) * C) * 2) + laneoff;
    }

    const char* xb = (const char*)xp;
    const char* wb = (const char*)wpk;

    f32x4 acc[4] = {};
#pragma unroll 2
    for (int p = 0; p < NP; ++p) {
        const int ta = 2 * p;
        const int tb = (2 * p + 1 < NTAPS) ? 2 * p + 1 : NTAPS - 1;
        const int kda = ta / (KH * KW), ra = ta % (KH * KW);
        const int kha = ra / KW,        kwa = ra % KW;
        const int kdb = tb / (KH * KW), rb = tb % (KH * KW);
        const int khb = rb / KW,        kwb = rb % KW;
        const unsigned toa = (unsigned)((kda * PLANEE + kha * ROWE + kwa * C) * 2);
        const unsigned tob = (unsigned)((kdb * PLANEE + khb * ROWE + kwb * C) * 2);
        const unsigned ts  = tsel ? tob : toa;

        const short8 a = *(const short8*)(wb + (unsigned)(p * 1024 + lane * 16));
#pragma unroll
        for (int r = 0; r < 4; ++r) {
            const short8 bf = *(const short8*)(xb + (off_r[r] + ts));
            acc[r] = __builtin_amdgcn_mfma_f32_16x16x32_bf16(a, bf, acc[r], 0, 0, 0);
        }
    }

    float sc[4], sh[4];
    if (BN) {
        const int cb = (lane >> 4) * 4;
        const f32x4 g  = *(const f32x4*)(bn_g + layer * C + cb);
        const f32x4 be = *(const f32x4*)(bn_b + layer * C + cb);
        const f32x4 m  = *(const f32x4*)(bn_m + layer * C + cb);
        const f32x4 v  = *(const f32x4*)(bn_v + layer * C + cb);
#pragma unroll
        for (int j = 0; j < 4; ++j) { sc[j] = g[j] / sqrtf(v[j] + 1e-5f); sh[j] = be[j] - m[j] * sc[j]; }
    } else {
#pragma unroll
        for (int j = 0; j < 4; ++j) { sc[j] = 1.f; sh[j] = 0.f; }
    }
#pragma unroll
    for (int r = 0; r < 4; ++r) {
        const int h = h0 + r;
        float* dst = F + (unsigned)(((d * HH + h) * WW + l15) * C + (lane >> 4) * 4);
        f32x4 val;
#pragma unroll
        for (int j = 0; j < 4; ++j) val[j] = acc[r][j] * sc[j] + sh[j];
        if (ACCUM) {
            const f32x4 old = *(const f32x4*)dst;
#pragma unroll
            for (int j = 0; j < 4; ++j) val[j] += old[j];
        }
        *(f32x4*)dst = val;
    }
}

// ---------------------------------------------------------------------------
// x (fp32 [ci][d][h][w]) -> padded bf16 [dp][hp][wp][ci]
// ---------------------------------------------------------------------------
__global__ __launch_bounds__(256)
void pack_x(const float* __restrict__ x, short* __restrict__ xp)
{
    const int b  = blockIdx.x;
    const int dp = b / HP_, hp = b % HP_;
    const int t  = threadIdx.x;
    const int d  = dp - 3, h = hp - 3;
    const bool inr = ((unsigned)d < (unsigned)DD) && ((unsigned)h < (unsigned)HH);
    short* row = xp + (unsigned)(dp * PLANEE + hp * ROWE);

    const int w = t & 15, ci = t >> 4;
    float v = 0.f;
    if (inr) v = x[ci * SP + d * HW + h * WW + w];
    __hip_bfloat16 hv = __float2bfloat16(v);
    row[(w + 2) * C + ci] = *(short*)&hv;
    if (t < 64) {
        const int pi = t >> 4;
        const int wp = (pi < 2) ? pi : (16 + pi);
        row[wp * C + (t & 15)] = 0;
    }
}

// ---------------------------------------------------------------------------
// F (fp32 [d][h][w][ci]) -> padded bf16 (optional relu); optional S += A2.
// ---------------------------------------------------------------------------
template <bool RELU, bool ADD>
__global__ __launch_bounds__(256)
void pack_f(float* __restrict__ S, const float* __restrict__ A2,
            short* __restrict__ P)
{
    const int b  = blockIdx.x;
    const int dp = b / HP_, hp = b % HP_;
    const int t  = threadIdx.x;
    const int d  = dp - 3, h = hp - 3;
    const bool inr = ((unsigned)d < (unsigned)DD) && ((unsigned)h < (unsigned)HH);
    short* row = P + (unsigned)(dp * PLANEE + hp * ROWE);

    const int ci = t & 15, w = t >> 4;
    float pv = 0.f;
    if (inr) {
        const unsigned idx = (unsigned)(((d * HH + h) * WW + w) * C + ci);
        const float v = S[idx];
        pv = RELU ? fmaxf(v, 0.f) : v;
        if (ADD) S[idx] = v + A2[idx];
    }
    __hip_bfloat16 hv = __float2bfloat16(pv);
    row[(w + 2) * C + ci] = *(short*)&hv;
    if (t < 64) {
        const int pi = t >> 4;
        const int wp = (pi < 2) ? pi : (16 + pi);
        row[wp * C + (t & 15)] = 0;
    }
}

// ---------------------------------------------------------------------------
// Old-style weight pack (linear tap pairs) for the small convs.
// ---------------------------------------------------------------------------
__global__ __launch_bounds__(256)
void pack_w(const float* __restrict__ src, short* __restrict__ dst,
            int KHW, int NTAPS)
{
    const int p  = blockIdx.x;
    const int t  = threadIdx.x;
    const int l  = t >> 2, jj = t & 3;
    const int co = l & 15, cih = (l >> 4) & 1, tp = l >> 5;
    const int tap = 2 * p + tp;
    unsigned out = 0;
#pragma unroll
    for (int s = 0; s < 2; ++s) {
        const int j  = jj * 2 + s;
        const int ci = cih * 8 + j;
        const float v = (tap < NTAPS) ? src[(co * C + ci) * KHW + tap] : 0.f;
        __hip_bfloat16 hv = __float2bfloat16(v);
        out |= ((unsigned)*(unsigned short*)&hv) << (16 * s);
    }
    ((unsigned*)dst)[p * 256 + l * 4 + jj] = out;
}

// ---------------------------------------------------------------------------
// kw-paired weight pack for the tile kernel: fragment order [kd*KH+kh][kwp].
// Element (p, lane l, j): co=l&15, kw=2*kwp+(l>>5) (>=KW -> 0), ci=((l>>4)&1)*8+j.
// ---------------------------------------------------------------------------
__global__ __launch_bounds__(256)
void pack_w_pairs(const float* __restrict__ src, short* __restrict__ dst,
                  int KW, int KWP, int KHW)
{
    const int p   = blockIdx.x;
    const int row = p / KWP, kwp = p % KWP;
    const int t   = threadIdx.x;
    const int l   = t >> 2, jj = t & 3;
    const int co  = l & 15, cih = (l >> 4) & 1, tp = l >> 5;
    const int kw  = 2 * kwp + tp;
    unsigned out = 0;
#pragma unroll
    for (int s = 0; s < 2; ++s) {
        const int j  = jj * 2 + s;
        const int ci = cih * 8 + j;
        const float v = (kw < KW) ? src[(co * C + ci) * KHW + row * KW + kw] : 0.f;
        __hip_bfloat16 hv = __float2bfloat16(v);
        out |= ((unsigned)*(unsigned short*)&hv) << (16 * s);
    }
    ((unsigned*)dst)[p * 256 + l * 4 + jj] = out;
}

// ---------------------------------------------------------------------------
// Final: out[co][d][h][w] = relu(F1[d][h][w][co])  (LDS 16x16 transpose)
// ---------------------------------------------------------------------------
__global__ __launch_bounds__(256)
void final_tr(const float* __restrict__ F, float* __restrict__ out)
{
    __shared__ float lds[16 * 17];
    const int b = blockIdx.x;
    const int d = b >> 3, hb = b & 7;
    const int t = threadIdx.x;
    for (int hh = 0; hh < 16; ++hh) {
        const int h = hb * 16 + hh;
        {
            const int ci = t & 15, w = t >> 4;
            const float v = F[(unsigned)(((d * HH + h) * WW + w) * C + ci)];
            lds[w * 17 + ci] = fmaxf(v, 0.f);
        }
        __syncthreads();
        {
            const int w = t & 15, co = t >> 4;
            out[(unsigned)(co * SP + d * HW + h * WW + w)] = lds[w * 17 + co];
        }
        __syncthreads();
    }
}

// ---------------------------------------------------------------------------
extern "C" void kernel_launch(void* const* d_in, const int* in_sizes, int n_in,
                              void* d_out, int out_size, void* d_ws, size_t ws_size,
                              hipStream_t stream)
{
    const float* x    = (const float*)d_in[0];
    const float* wsrc[11] = {
        (const float*)d_in[1],  (const float*)d_in[2],  (const float*)d_in[3],
        (const float*)d_in[4],  (const float*)d_in[5],  (const float*)d_in[6],
        (const float*)d_in[7],  (const float*)d_in[8],  (const float*)d_in[9],
        (const float*)d_in[10], (const float*)d_in[11] };
    const float* bng  = (const float*)d_in[12];
    const float* bnb  = (const float*)d_in[13];
    const float* bnm  = (const float*)d_in[14];
    const float* bnv  = (const float*)d_in[15];

    short* XP  = (short*)d_ws;
    short* P2  = XP + PADE;
    float* F1  = (float*)(P2 + PADE);
    short* WPK = (short*)(F1 + TOT);
    float* F2  = (float*)d_out;           // fp32 scratch; fully rewritten at end

    // Per weight: style (0=old linear pairs, 1=kw-pairs), pair count, KHW, KW.
    // idx:           w1 w2 w3  w4   w5 w6  w7   wch wr1 wr2 wr3
    const int style[11] = {0, 0, 1,  1,   0, 1,  1,   0,  0,  1,  1};
    const int npair[11] = {5, 5, 50, 147, 5, 50, 147, 1,  5,  50, 147};
    const int khw[11]   = {9, 9, 75, 245, 9, 75, 245, 1,  9,  75, 245};
    const int kws[11]   = {1, 1, 3,  5,   1, 3,  5,   1,  1,  3,  5};
    int woff[11]; { int o = 0; for (int i = 0; i < 11; ++i) { woff[i] = o; o += npair[i] * 512; } }

    const dim3 blk(256);
    const dim3 pgrid(DP_ * HP_);          // 17956
    const dim3 sgrid(DD * 8);             // 1024 (small-conv + final_tr grid)
    const dim3 tgrid((DD / 2) * (HH / 32)); // 256  (tile-conv grid)

    for (int i = 0; i < 11; ++i) {
        if (style[i])
            pack_w_pairs<<<dim3(npair[i]), blk, 0, stream>>>(wsrc[i], WPK + woff[i],
                                                             kws[i], (kws[i] + 1) / 2, khw[i]);
        else
            pack_w<<<dim3(npair[i]), blk, 0, stream>>>(wsrc[i], WPK + woff[i], khw[i], khw[i]);
    }

    pack_x<<<pgrid, blk, 0, stream>>>(x, XP);

    // x1 = cbn(x, w1, 0) -> F1
    conv_mfma<3,3,1,9,false,true><<<sgrid, blk, 0, stream>>>(XP, WPK + woff[0], bng, bnb, bnm, bnv, 0, F1);
    pack_f<false,false><<<pgrid, blk, 0, stream>>>(F1, nullptr, P2);
    // F2 = x2 + x3 + x4
    conv_mfma<3,3,1,9,false,true><<<sgrid, blk, 0, stream>>>(P2, WPK + woff[1], bng, bnb, bnm, bnv, 1, F2);
    conv_mfma_tile<5,5,3,true,true><<<tgrid, blk, 0, stream>>>(P2, WPK + woff[2], bng, bnb, bnm, bnv, 2, F2);
    conv_mfma_tile<7,7,5,true,true><<<tgrid, blk, 0, stream>>>(P2, WPK + woff[3], bng, bnb, bnm, bnv, 3, F2);
    // t1p = relu(F2); F2 += F1
    pack_f<true,true><<<pgrid, blk, 0, stream>>>(F2, F1, P2);
    // F2 += x5 + x6 + x7
    conv_mfma<3,3,1,9,true,true><<<sgrid, blk, 0, stream>>>(P2, WPK + woff[4], bng, bnb, bnm, bnv, 4, F2);
    conv_mfma_tile<5,5,3,true,true><<<tgrid, blk, 0, stream>>>(P2, WPK + woff[5], bng, bnb, bnm, bnv, 5, F2);
    conv_mfma_tile<7,7,5,true,true><<<tgrid, blk, 0, stream>>>(P2, WPK + woff[6], bng, bnb, bnm, bnv, 6, F2);
    // xsp = relu(F2)
    pack_f<true,false><<<pgrid, blk, 0, stream>>>(F2, nullptr, P2);
    // F1 += y0 (1x1x1, no BN)
    conv_mfma<1,1,1,1,true,false><<<sgrid, blk, 0, stream>>>(P2, WPK + woff[7], bng, bnb, bnm, bnv, 0, F1);
    // F1 += y1, y2, y3
    conv_mfma<3,3,1,9,true,true><<<sgrid, blk, 0, stream>>>(XP, WPK + woff[8], bng, bnb, bnm, bnv, 7, F1);
    conv_mfma_tile<5,5,3,true,true><<<tgrid, blk, 0, stream>>>(XP, WPK + woff[9], bng, bnb, bnm, bnv, 8, F1);
    conv_mfma_tile<7,7,5,true,true><<<tgrid, blk, 0, stream>>>(XP, WPK + woff[10], bng, bnb, bnm, bnv, 9, F1);
    // out = relu(F1) transposed to [co][d][h][w]
    final_tr<<<sgrid, blk, 0, stream>>>(F1, (float*)d_out);

    (void)in_sizes; (void)n_in; (void)out_size; (void)ws_size;
}

// Round 7
// 294.892 us; speedup vs baseline: 45.4200x; 1.2135x over previous
//
#include <hip/hip_runtime.h>
#include <hip/hip_bf16.h>

typedef __attribute__((ext_vector_type(8))) short short8;   // 8 bf16 = 4 VGPRs
typedef __attribute__((ext_vector_type(4))) float f32x4;

constexpr int C  = 16;
constexpr int DD = 128, HH = 128, WW = 16;
constexpr int HW = HH * WW;        // 2048
constexpr int SP = DD * HW;        // 262144
constexpr int TOT = C * SP;        // 4194304

// Padded bf16 activation layout: [dp=134][hp=134][wp=20][ci=16]
constexpr int WP_ = 20, HP_ = 134, DP_ = 134;
constexpr int ROWE   = WP_ * C;        // 320
constexpr int PLANEE = HP_ * ROWE;     // 42880
constexpr int PADE   = DP_ * PLANEE;   // 5,745,920 elems

// ---------------------------------------------------------------------------
// Tiled MFMA conv with dz-parity K-split wave pairs (5x5x3 / 7x7x5 convs).
// A pair of waves shares one TD=2 x TH=8 output tile; member m handles
// dz-sweep steps u = m, m+2, ... (each (ad,kd) lands at unique u=kd+ad, so
// the parity split is an exact work partition). Partials merged via LDS.
// Block = 512 thr = 4 pairs covering 2d x 32h; grid 256 -> 2 waves/SIMD.
// ---------------------------------------------------------------------------
template <int KD, int KH, int KW, bool ACCUM, bool BN>
__global__ __launch_bounds__(512, 2)
void conv_mfma_tile(const short* __restrict__ xp, const short* __restrict__ wpk,
                    const float* __restrict__ bn_g, const float* __restrict__ bn_b,
                    const float* __restrict__ bn_m, const float* __restrict__ bn_v,
                    int layer, float* __restrict__ F)
{
    constexpr int PD = (KD - 1) / 2, PH = (KH - 1) / 2, PW = (KW - 1) / 2;
    constexpr int KWP = (KW + 1) / 2;
    constexpr int TD = 2, TH = 8;
    constexpr int NU = TD + KD - 1;    // dz planes swept
    constexpr int NB = TH + KH - 1;    // B halo rows per dz

    __shared__ float mlds[4][TD][TH][64][4];   // 64 KB: pair merge buffers

    const int b    = blockIdx.x;
    const int dblk = b >> 2, hb = b & 3;
    const int tid  = threadIdx.x;
    const int wid  = tid >> 6, lane = tid & 63;
    const int pid  = wid >> 1, m = wid & 1;     // pair id, member
    const int d0   = dblk * TD;
    const int h0   = hb * 32 + pid * TH;

    const int l15  = lane & 15;
    const int cih  = (lane >> 4) & 1;
    const int tsel = lane >> 5;

    const char* xb = (const char*)xp;
    const char* wb = (const char*)wpk;

    f32x4 acc[TD][TH] = {};

#pragma unroll 1
    for (int kwp = 0; kwp < KWP; ++kwp) {
        const int kwa = 2 * kwp;
        const int kwb = (2 * kwp + 1 < KW) ? 2 * kwp + 1 : KW - 1;  // pad: A=0
        const unsigned laneoff =
            (unsigned)((l15 + (tsel ? kwb : kwa) + (2 - PW)) * 32 + cih * 16);

#pragma unroll 1
        for (int u = m; u < NU; u += 2) {
            const unsigned rowbase =
                (unsigned)((((d0 + u + (3 - PD)) * HP_ + (h0 + (3 - PH))) * ROWE) * 2)
                + laneoff;
            short8 Bf[NB];
#pragma unroll
            for (int rB = 0; rB < NB; ++rB)
                Bf[rB] = *(const short8*)(xb + rowbase + (unsigned)(rB * ROWE * 2));

#pragma unroll
            for (int ad = 0; ad < TD; ++ad) {
                const int kd = u - ad;
                if (kd < 0 || kd >= KD) continue;       // wave-uniform
#pragma unroll
                for (int kh = 0; kh < KH; ++kh) {
                    const short8 a = *(const short8*)(
                        wb + (unsigned)((((kd * KH + kh) * KWP) + kwp) * 1024 + lane * 16));
#pragma unroll
                    for (int r = 0; r < TH; ++r)
                        acc[ad][r] = __builtin_amdgcn_mfma_f32_16x16x32_bf16(
                            a, Bf[r + kh], acc[ad][r], 0, 0, 0);
                }
            }
        }
    }

    // K-split merge: member1 publishes partials; member0 reduces + epilogue.
    if (m == 1) {
#pragma unroll
        for (int ad = 0; ad < TD; ++ad)
#pragma unroll
            for (int r = 0; r < TH; ++r)
                *(f32x4*)&mlds[pid][ad][r][lane][0] = acc[ad][r];
    }
    __syncthreads();
    if (m == 1) return;
#pragma unroll
    for (int ad = 0; ad < TD; ++ad)
#pragma unroll
        for (int r = 0; r < TH; ++r) {
            const f32x4 o = *(const f32x4*)&mlds[pid][ad][r][lane][0];
#pragma unroll
            for (int j = 0; j < 4; ++j) acc[ad][r][j] += o[j];
        }

    float sc[4], sh[4];
    if (BN) {
        const int cb = (lane >> 4) * 4;
        const f32x4 g  = *(const f32x4*)(bn_g + layer * C + cb);
        const f32x4 be = *(const f32x4*)(bn_b + layer * C + cb);
        const f32x4 mm = *(const f32x4*)(bn_m + layer * C + cb);
        const f32x4 v  = *(const f32x4*)(bn_v + layer * C + cb);
#pragma unroll
        for (int j = 0; j < 4; ++j) { sc[j] = g[j] / sqrtf(v[j] + 1e-5f); sh[j] = be[j] - mm[j] * sc[j]; }
    } else {
#pragma unroll
        for (int j = 0; j < 4; ++j) { sc[j] = 1.f; sh[j] = 0.f; }
    }
#pragma unroll
    for (int ad = 0; ad < TD; ++ad)
#pragma unroll
        for (int r = 0; r < TH; ++r) {
            const int d = d0 + ad, h = h0 + r;
            float* dst = F + (unsigned)(((d * HH + h) * WW + l15) * C + (lane >> 4) * 4);
            f32x4 val;
#pragma unroll
            for (int j = 0; j < 4; ++j) val[j] = acc[ad][r][j] * sc[j] + sh[j];
            if (ACCUM) {
                const f32x4 old = *(const f32x4*)dst;
#pragma unroll
                for (int j = 0; j < 4; ++j) val[j] += old[j];
            }
            *(f32x4*)dst = val;
        }
}

// ---------------------------------------------------------------------------
// Small convs (3x3x1 taps=9, 1x1x1 taps=1): round-5 kernel.
// ---------------------------------------------------------------------------
template <int KD, int KH, int KW, int NTAPS, bool ACCUM, bool BN>
__global__ __launch_bounds__(256, 4)
void conv_mfma(const short* __restrict__ xp, const short* __restrict__ wpk,
               const float* __restrict__ bn_g, const float* __restrict__ bn_b,
               const float* __restrict__ bn_m, const float* __restrict__ bn_v,
               int layer, float* __restrict__ F)
{
    constexpr int PD = (KD - 1) / 2, PH = (KH - 1) / 2, PW = (KW - 1) / 2;
    constexpr int NP = (NTAPS + 1) / 2;

    const int b    = blockIdx.x;
    const int d    = b >> 3, hb = b & 7;
    const int tid  = threadIdx.x;
    const int wid  = tid >> 6, lane = tid & 63;
    const int h0   = hb * 16 + wid * 4;

    const int l15  = lane & 15;
    const int cih  = (lane >> 4) & 1;
    const int tsel = lane >> 5;
    const unsigned laneoff = (unsigned)(l15 * 32 + cih * 16);

    unsigned off_r[4];
#pragma unroll
    for (int r = 0; r < 4; ++r) {
        const int h = h0 + r;
        off_r[r] = (unsigned)((((d + (3 - PD)) * HP_ + (h + (3 - PH))) * ROWE
                               + (2 - PW) * C) * 2) + laneoff;
    }

    const char* xb = (const char*)xp;
    const char* wb = (const char*)wpk;

    f32x4 acc[4] = {};
#pragma unroll 2
    for (int p = 0; p < NP; ++p) {
        const int ta = 2 * p;
        const int tb = (2 * p + 1 < NTAPS) ? 2 * p + 1 : NTAPS - 1;
        const int kda = ta / (KH * KW), ra = ta % (KH * KW);
        const int kha = ra / KW,        kwa = ra % KW;
        const int kdb = tb / (KH * KW), rb = tb % (KH * KW);
        const int khb = rb / KW,        kwb = rb % KW;
        const unsigned toa = (unsigned)((kda * PLANEE + kha * ROWE + kwa * C) * 2);
        const unsigned tob = (unsigned)((kdb * PLANEE + khb * ROWE + kwb * C) * 2);
        const unsigned ts  = tsel ? tob : toa;

        const short8 a = *(const short8*)(wb + (unsigned)(p * 1024 + lane * 16));
#pragma unroll
        for (int r = 0; r < 4; ++r) {
            const short8 bf = *(const short8*)(xb + (off_r[r] + ts));
            acc[r] = __builtin_amdgcn_mfma_f32_16x16x32_bf16(a, bf, acc[r], 0, 0, 0);
        }
    }

    float sc[4], sh[4];
    if (BN) {
        const int cb = (lane >> 4) * 4;
        const f32x4 g  = *(const f32x4*)(bn_g + layer * C + cb);
        const f32x4 be = *(const f32x4*)(bn_b + layer * C + cb);
        const f32x4 m  = *(const f32x4*)(bn_m + layer * C + cb);
        const f32x4 v  = *(const f32x4*)(bn_v + layer * C + cb);
#pragma unroll
        for (int j = 0; j < 4; ++j) { sc[j] = g[j] / sqrtf(v[j] + 1e-5f); sh[j] = be[j] - m[j] * sc[j]; }
    } else {
#pragma unroll
        for (int j = 0; j < 4; ++j) { sc[j] = 1.f; sh[j] = 0.f; }
    }
#pragma unroll
    for (int r = 0; r < 4; ++r) {
        const int h = h0 + r;
        float* dst = F + (unsigned)(((d * HH + h) * WW + l15) * C + (lane >> 4) * 4);
        f32x4 val;
#pragma unroll
        for (int j = 0; j < 4; ++j) val[j] = acc[r][j] * sc[j] + sh[j];
        if (ACCUM) {
            const f32x4 old = *(const f32x4*)dst;
#pragma unroll
            for (int j = 0; j < 4; ++j) val[j] += old[j];
        }
        *(f32x4*)dst = val;
    }
}

// ---------------------------------------------------------------------------
__global__ __launch_bounds__(256)
void pack_x(const float* __restrict__ x, short* __restrict__ xp)
{
    const int b  = blockIdx.x;
    const int dp = b / HP_, hp = b % HP_;
    const int t  = threadIdx.x;
    const int d  = dp - 3, h = hp - 3;
    const bool inr = ((unsigned)d < (unsigned)DD) && ((unsigned)h < (unsigned)HH);
    short* row = xp + (unsigned)(dp * PLANEE + hp * ROWE);

    const int w = t & 15, ci = t >> 4;
    float v = 0.f;
    if (inr) v = x[ci * SP + d * HW + h * WW + w];
    __hip_bfloat16 hv = __float2bfloat16(v);
    row[(w + 2) * C + ci] = *(short*)&hv;
    if (t < 64) {
        const int pi = t >> 4;
        const int wp = (pi < 2) ? pi : (16 + pi);
        row[wp * C + (t & 15)] = 0;
    }
}

template <bool RELU, bool ADD>
__global__ __launch_bounds__(256)
void pack_f(float* __restrict__ S, const float* __restrict__ A2,
            short* __restrict__ P)
{
    const int b  = blockIdx.x;
    const int dp = b / HP_, hp = b % HP_;
    const int t  = threadIdx.x;
    const int d  = dp - 3, h = hp - 3;
    const bool inr = ((unsigned)d < (unsigned)DD) && ((unsigned)h < (unsigned)HH);
    short* row = P + (unsigned)(dp * PLANEE + hp * ROWE);

    const int ci = t & 15, w = t >> 4;
    float pv = 0.f;
    if (inr) {
        const unsigned idx = (unsigned)(((d * HH + h) * WW + w) * C + ci);
        const float v = S[idx];
        pv = RELU ? fmaxf(v, 0.f) : v;
        if (ADD) S[idx] = v + A2[idx];
    }
    __hip_bfloat16 hv = __float2bfloat16(pv);
    row[(w + 2) * C + ci] = *(short*)&hv;
    if (t < 64) {
        const int pi = t >> 4;
        const int wp = (pi < 2) ? pi : (16 + pi);
        row[wp * C + (t & 15)] = 0;
    }
}

__global__ __launch_bounds__(256)
void pack_w(const float* __restrict__ src, short* __restrict__ dst,
            int KHW, int NTAPS)
{
    const int p  = blockIdx.x;
    const int t  = threadIdx.x;
    const int l  = t >> 2, jj = t & 3;
    const int co = l & 15, cih = (l >> 4) & 1, tp = l >> 5;
    const int tap = 2 * p + tp;
    unsigned out = 0;
#pragma unroll
    for (int s = 0; s < 2; ++s) {
        const int j  = jj * 2 + s;
        const int ci = cih * 8 + j;
        const float v = (tap < NTAPS) ? src[(co * C + ci) * KHW + tap] : 0.f;
        __hip_bfloat16 hv = __float2bfloat16(v);
        out |= ((unsigned)*(unsigned short*)&hv) << (16 * s);
    }
    ((unsigned*)dst)[p * 256 + l * 4 + jj] = out;
}

__global__ __launch_bounds__(256)
void pack_w_pairs(const float* __restrict__ src, short* __restrict__ dst,
                  int KW, int KWP, int KHW)
{
    const int p   = blockIdx.x;
    const int row = p / KWP, kwp = p % KWP;
    const int t   = threadIdx.x;
    const int l   = t >> 2, jj = t & 3;
    const int co  = l & 15, cih = (l >> 4) & 1, tp = l >> 5;
    const int kw  = 2 * kwp + tp;
    unsigned out = 0;
#pragma unroll
    for (int s = 0; s < 2; ++s) {
        const int j  = jj * 2 + s;
        const int ci = cih * 8 + j;
        const float v = (kw < KW) ? src[(co * C + ci) * KHW + row * KW + kw] : 0.f;
        __hip_bfloat16 hv = __float2bfloat16(v);
        out |= ((unsigned)*(unsigned short*)&hv) << (16 * s);
    }
    ((unsigned*)dst)[p * 256 + l * 4 + jj] = out;
}

__global__ __launch_bounds__(256)
void final_tr(const float* __restrict__ F, float* __restrict__ out)
{
    __shared__ float lds[16 * 17];
    const int b = blockIdx.x;
    const int d = b >> 3, hb = b & 7;
    const int t = threadIdx.x;
    for (int hh = 0; hh < 16; ++hh) {
        const int h = hb * 16 + hh;
        {
            const int ci = t & 15, w = t >> 4;
            const float v = F[(unsigned)(((d * HH + h) * WW + w) * C + ci)];
            lds[w * 17 + ci] = fmaxf(v, 0.f);
        }
        __syncthreads();
        {
            const int w = t & 15, co = t >> 4;
            out[(unsigned)(co * SP + d * HW + h * WW + w)] = lds[w * 17 + co];
        }
        __syncthreads();
    }
}

// ---------------------------------------------------------------------------
extern "C" void kernel_launch(void* const* d_in, const int* in_sizes, int n_in,
                              void* d_out, int out_size, void* d_ws, size_t ws_size,
                              hipStream_t stream)
{
    const float* x    = (const float*)d_in[0];
    const float* wsrc[11] = {
        (const float*)d_in[1],  (const float*)d_in[2],  (const float*)d_in[3],
        (const float*)d_in[4],  (const float*)d_in[5],  (const float*)d_in[6],
        (const float*)d_in[7],  (const float*)d_in[8],  (const float*)d_in[9],
        (const float*)d_in[10], (const float*)d_in[11] };
    const float* bng  = (const float*)d_in[12];
    const float* bnb  = (const float*)d_in[13];
    const float* bnm  = (const float*)d_in[14];
    const float* bnv  = (const float*)d_in[15];

    short* XP  = (short*)d_ws;
    short* P2  = XP + PADE;
    float* F1  = (float*)(P2 + PADE);
    short* WPK = (short*)(F1 + TOT);
    float* F2  = (float*)d_out;           // fp32 scratch; fully rewritten at end

    // idx:           w1 w2 w3  w4   w5 w6  w7   wch wr1 wr2 wr3
    const int style[11] = {0, 0, 1,  1,   0, 1,  1,   0,  0,  1,  1};
    const int npair[11] = {5, 5, 50, 147, 5, 50, 147, 1,  5,  50, 147};
    const int khw[11]   = {9, 9, 75, 245, 9, 75, 245, 1,  9,  75, 245};
    const int kws[11]   = {1, 1, 3,  5,   1, 3,  5,   1,  1,  3,  5};
    int woff[11]; { int o = 0; for (int i = 0; i < 11; ++i) { woff[i] = o; o += npair[i] * 512; } }

    const dim3 blk(256), blk512(512);
    const dim3 pgrid(DP_ * HP_);            // 17956
    const dim3 sgrid(DD * 8);               // 1024
    const dim3 tgrid((DD / 2) * (HH / 32)); // 256

    for (int i = 0; i < 11; ++i) {
        if (style[i])
            pack_w_pairs<<<dim3(npair[i]), blk, 0, stream>>>(wsrc[i], WPK + woff[i],
                                                             kws[i], (kws[i] + 1) / 2, khw[i]);
        else
            pack_w<<<dim3(npair[i]), blk, 0, stream>>>(wsrc[i], WPK + woff[i], khw[i], khw[i]);
    }

    pack_x<<<pgrid, blk, 0, stream>>>(x, XP);

    // x1 = cbn(x, w1, 0) -> F1
    conv_mfma<3,3,1,9,false,true><<<sgrid, blk, 0, stream>>>(XP, WPK + woff[0], bng, bnb, bnm, bnv, 0, F1);
    pack_f<false,false><<<pgrid, blk, 0, stream>>>(F1, nullptr, P2);
    // F2 = x2 + x3 + x4
    conv_mfma<3,3,1,9,false,true><<<sgrid, blk, 0, stream>>>(P2, WPK + woff[1], bng, bnb, bnm, bnv, 1, F2);
    conv_mfma_tile<5,5,3,true,true><<<tgrid, blk512, 0, stream>>>(P2, WPK + woff[2], bng, bnb, bnm, bnv, 2, F2);
    conv_mfma_tile<7,7,5,true,true><<<tgrid, blk512, 0, stream>>>(P2, WPK + woff[3], bng, bnb, bnm, bnv, 3, F2);
    // t1p = relu(F2); F2 += F1
    pack_f<true,true><<<pgrid, blk, 0, stream>>>(F2, F1, P2);
    // F2 += x5 + x6 + x7
    conv_mfma<3,3,1,9,true,true><<<sgrid, blk, 0, stream>>>(P2, WPK + woff[4], bng, bnb, bnm, bnv, 4, F2);
    conv_mfma_tile<5,5,3,true,true><<<tgrid, blk512, 0, stream>>>(P2, WPK + woff[5], bng, bnb, bnm, bnv, 5, F2);
    conv_mfma_tile<7,7,5,true,true><<<tgrid, blk512, 0, stream>>>(P2, WPK + woff[6], bng, bnb, bnm, bnv, 6, F2);
    // xsp = relu(F2)
    pack_f<true,false><<<pgrid, blk, 0, stream>>>(F2, nullptr, P2);
    // F1 += y0 (1x1x1, no BN)
    conv_mfma<1,1,1,1,true,false><<<sgrid, blk, 0, stream>>>(P2, WPK + woff[7], bng, bnb, bnm, bnv, 0, F1);
    // F1 += y1, y2, y3
    conv_mfma<3,3,1,9,true,true><<<sgrid, blk, 0, stream>>>(XP, WPK + woff[8], bng, bnb, bnm, bnv, 7, F1);
    conv_mfma_tile<5,5,3,true,true><<<tgrid, blk512, 0, stream>>>(XP, WPK + woff[9], bng, bnb, bnm, bnv, 8, F1);
    conv_mfma_tile<7,7,5,true,true><<<tgrid, blk512, 0, stream>>>(XP, WPK + woff[10], bng, bnb, bnm, bnv, 9, F1);
    // out = relu(F1) transposed to [co][d][h][w]
    final_tr<<<sgrid, blk, 0, stream>>>(F1, (float*)d_out);

    (void)in_sizes; (void)n_in; (void)out_size; (void)ws_size;
}

// Round 8
// 261.961 us; speedup vs baseline: 51.1297x; 1.1257x over previous
//
#include <hip/hip_runtime.h>
#include <hip/hip_bf16.h>

typedef __attribute__((ext_vector_type(8))) short short8;   // 8 bf16 = 4 VGPRs
typedef __attribute__((ext_vector_type(4))) float f32x4;

constexpr int C  = 16;
constexpr int DD = 128, HH = 128, WW = 16;
constexpr int HW = HH * WW;        // 2048
constexpr int SP = DD * HW;        // 262144
constexpr int TOT = C * SP;        // 4194304

// Padded bf16 activation layout: [dp=134][hp=134][wp=20][ci=16]
constexpr int WP_ = 20, HP_ = 134, DP_ = 134;
constexpr int ROWE   = WP_ * C;        // 320 elems (640 B) per row
constexpr int PLANEE = HP_ * ROWE;     // 42880
constexpr int PADE   = DP_ * PLANEE;   // 5,745,920 elems

using gas_ptr = const __attribute__((address_space(1))) void*;
using las_ptr = __attribute__((address_space(3))) void*;

// ---------------------------------------------------------------------------
// LDS-staged tiled MFMA conv + fused BN (5x5x3 / 7x7x5).
// Block 256 thr = 4 waves = 2 K-split pairs; pair tile 2d x 8h; block 2d x 16h.
// Grid 512 = 64 dblk x 8 hb -> 2 blocks/CU, 8 waves/CU.
// Per u-pair: both members' dz-planes (2 x NR full 640B rows) staged to LDS,
// double-buffered, raw s_barrier + counted vmcnt so prefetch stays in flight.
// B-fragments then come from LDS (128 B/cyc) instead of L1 (64 B/cyc).
// ---------------------------------------------------------------------------
template <int KD, int KH, int KW, bool ACCUM, bool BN>
__global__ __launch_bounds__(256, 2)
void conv_tile_lds(const short* __restrict__ xp, const short* __restrict__ wpk,
                   const float* __restrict__ bn_g, const float* __restrict__ bn_b,
                   const float* __restrict__ bn_m, const float* __restrict__ bn_v,
                   int layer, float* __restrict__ F)
{
    constexpr int PD = (KD - 1) / 2, PH = (KH - 1) / 2, PW = (KW - 1) / 2;
    constexpr int KWP = (KW + 1) / 2;
    constexpr int NU  = 2 + KD - 1;        // dz planes per tile sweep (even)
    constexpr int NUP = NU / 2;            // u-pair steps
    constexpr int NB  = 8 + KH - 1;        // B halo rows per wave per plane
    constexpr int NR  = 16 + 2 * PH;       // staged rows per plane
    constexpr int NCHP = NR * 40;          // 16B chunks per plane (row = 40)
    constexpr int NCH  = 2 * NCHP;         // chunks per u-pair stage
    constexpr int BUFSZ = 7 * 256 * 16;    // 28672 B per buffer (7 iters)
    static_assert(NCH <= 7 * 256, "stage fits in 7 iterations");

    __shared__ alignas(16) char smem[2 * BUFSZ];   // 57344 B

    const int b    = blockIdx.x;
    const int dblk = b >> 3, hb = b & 7;
    const int d0   = dblk * 2;
    const int tid  = threadIdx.x;
    const int wid  = tid >> 6, lane = tid & 63;
    const int pid  = wid >> 1, m = wid & 1;        // pair id, K-split member
    const int l15  = lane & 15;
    const int cih  = (lane >> 4) & 1;
    const int tsel = lane >> 5;

    const char* xb = (const char*)xp;
    const char* wb = (const char*)wpk;
    const int hp0  = hb * 16 + (3 - PH);           // first staged padded-h row

    // Stage both planes of u-pair `up` into buffer `buf`: exactly 7
    // global_load_lds per wave (tail lanes clamped -> deterministic vmcnt).
    auto stage = [&](int buf, int up) {
#pragma unroll
        for (int it = 0; it < 7; ++it) {
            int chunk = it * 256 + tid;
            int cc = chunk < NCH ? chunk : NCH - 1;
            int pl = (cc >= NCHP) ? 1 : 0;
            int cp = cc - pl * NCHP;
            const char* g = xb
                + (size_t)((d0 + 2 * up + pl + (3 - PD)) * PLANEE + hp0 * ROWE) * 2
                + (size_t)cp * 16;
            void* l = (void*)(smem + buf * BUFSZ + (it * 256 + wid * 64) * 16);
            __builtin_amdgcn_global_load_lds((gas_ptr)g, (las_ptr)l, 16, 0, 0);
        }
    };

    f32x4 acc[2][8] = {};

    stage(0, 0);
#pragma unroll 1
    for (int up = 0; up < NUP; ++up) {
        const int cur = up & 1;
        if (up + 1 < NUP) {
            stage(cur ^ 1, up + 1);
            asm volatile("s_waitcnt vmcnt(7)" ::: "memory");   // current buf done
        } else {
            asm volatile("s_waitcnt vmcnt(0)" ::: "memory");
        }
        __builtin_amdgcn_s_barrier();                          // buf[cur] valid for all

        const int u = 2 * up + m;
        const char* lb = smem + cur * BUFSZ + m * (NR * 640) + pid * 8 * 640;
#pragma unroll
        for (int kwp = 0; kwp < KWP; ++kwp) {
            const int kwa = 2 * kwp;
            const int kwb_ = (2 * kwp + 1 < KW) ? 2 * kwp + 1 : KW - 1;
            const unsigned laneoff =
                (unsigned)((l15 + (tsel ? kwb_ : kwa) + (2 - PW)) * 32 + cih * 16);
            short8 Bf[NB];
#pragma unroll
            for (int rB = 0; rB < NB; ++rB)
                Bf[rB] = *(const short8*)(lb + rB * 640 + laneoff);
#pragma unroll
            for (int ad = 0; ad < 2; ++ad) {
                const int kd = u - ad;
                if (kd < 0 || kd >= KD) continue;              // wave-uniform
#pragma unroll
                for (int kh = 0; kh < KH; ++kh) {
                    const short8 a = *(const short8*)(
                        wb + (unsigned)(((kd * KH + kh) * KWP + kwp) * 1024 + lane * 16));
#pragma unroll
                    for (int r = 0; r < 8; ++r)
                        acc[ad][r] = __builtin_amdgcn_mfma_f32_16x16x32_bf16(
                            a, Bf[r + kh], acc[ad][r], 0, 0, 0);
                }
            }
        }
        __builtin_amdgcn_s_barrier();                          // all reads of buf[cur] done
    }

    // K-split merge via LDS overlay (staging fully drained above).
    float* mlds = (float*)smem;
    if (m == 1) {
#pragma unroll
        for (int ad = 0; ad < 2; ++ad)
#pragma unroll
            for (int r = 0; r < 8; ++r)
                *(f32x4*)&mlds[(((pid * 2 + ad) * 8 + r) * 64 + lane) * 4] = acc[ad][r];
    }
    __syncthreads();
    if (m == 1) return;
#pragma unroll
    for (int ad = 0; ad < 2; ++ad)
#pragma unroll
        for (int r = 0; r < 8; ++r) {
            const f32x4 o = *(const f32x4*)&mlds[(((pid * 2 + ad) * 8 + r) * 64 + lane) * 4];
#pragma unroll
            for (int j = 0; j < 4; ++j) acc[ad][r][j] += o[j];
        }

    float sc[4], sh[4];
    if (BN) {
        const int cb = (lane >> 4) * 4;
        const f32x4 g  = *(const f32x4*)(bn_g + layer * C + cb);
        const f32x4 be = *(const f32x4*)(bn_b + layer * C + cb);
        const f32x4 mm = *(const f32x4*)(bn_m + layer * C + cb);
        const f32x4 v  = *(const f32x4*)(bn_v + layer * C + cb);
#pragma unroll
        for (int j = 0; j < 4; ++j) { sc[j] = g[j] / sqrtf(v[j] + 1e-5f); sh[j] = be[j] - mm[j] * sc[j]; }
    } else {
#pragma unroll
        for (int j = 0; j < 4; ++j) { sc[j] = 1.f; sh[j] = 0.f; }
    }
    const int h0 = hb * 16 + pid * 8;
#pragma unroll
    for (int ad = 0; ad < 2; ++ad)
#pragma unroll
        for (int r = 0; r < 8; ++r) {
            const int d = d0 + ad, h = h0 + r;
            float* dst = F + (unsigned)(((d * HH + h) * WW + l15) * C + (lane >> 4) * 4);
            f32x4 val;
#pragma unroll
            for (int j = 0; j < 4; ++j) val[j] = acc[ad][r][j] * sc[j] + sh[j];
            if (ACCUM) {
                const f32x4 old = *(const f32x4*)dst;
#pragma unroll
                for (int j = 0; j < 4; ++j) val[j] += old[j];
            }
            *(f32x4*)dst = val;
        }
}

// ---------------------------------------------------------------------------
// Small convs (3x3x1 taps=9, 1x1x1 taps=1): round-5 kernel.
// ---------------------------------------------------------------------------
template <int KD, int KH, int KW, int NTAPS, bool ACCUM, bool BN>
__global__ __launch_bounds__(256, 4)
void conv_mfma(const short* __restrict__ xp, const short* __restrict__ wpk,
               const float* __restrict__ bn_g, const float* __restrict__ bn_b,
               const float* __restrict__ bn_m, const float* __restrict__ bn_v,
               int layer, float* __restrict__ F)
{
    constexpr int PD = (KD - 1) / 2, PH = (KH - 1) / 2, PW = (KW - 1) / 2;
    constexpr int NP = (NTAPS + 1) / 2;

    const int b    = blockIdx.x;
    const int d    = b >> 3, hb = b & 7;
    const int tid  = threadIdx.x;
    const int wid  = tid >> 6, lane = tid & 63;
    const int h0   = hb * 16 + wid * 4;

    const int l15  = lane & 15;
    const int cih  = (lane >> 4) & 1;
    const int tsel = lane >> 5;
    const unsigned laneoff = (unsigned)(l15 * 32 + cih * 16);

    unsigned off_r[4];
#pragma unroll
    for (int r = 0; r < 4; ++r) {
        const int h = h0 + r;
        off_r[r] = (unsigned)((((d + (3 - PD)) * HP_ + (h + (3 - PH))) * ROWE
                               + (2 - PW) * C) * 2) + laneoff;
    }

    const char* xb = (const char*)xp;
    const char* wb = (const char*)wpk;

    f32x4 acc[4] = {};
#pragma unroll 2
    for (int p = 0; p < NP; ++p) {
        const int ta = 2 * p;
        const int tb = (2 * p + 1 < NTAPS) ? 2 * p + 1 : NTAPS - 1;
        const int kda = ta / (KH * KW), ra = ta % (KH * KW);
        const int kha = ra / KW,        kwa = ra % KW;
        const int kdb = tb / (KH * KW), rb = tb % (KH * KW);
        const int khb = rb / KW,        kwb = rb % KW;
        const unsigned toa = (unsigned)((kda * PLANEE + kha * ROWE + kwa * C) * 2);
        const unsigned tob = (unsigned)((kdb * PLANEE + khb * ROWE + kwb * C) * 2);
        const unsigned ts  = tsel ? tob : toa;

        const short8 a = *(const short8*)(wb + (unsigned)(p * 1024 + lane * 16));
#pragma unroll
        for (int r = 0; r < 4; ++r) {
            const short8 bf = *(const short8*)(xb + (off_r[r] + ts));
            acc[r] = __builtin_amdgcn_mfma_f32_16x16x32_bf16(a, bf, acc[r], 0, 0, 0);
        }
    }

    float sc[4], sh[4];
    if (BN) {
        const int cb = (lane >> 4) * 4;
        const f32x4 g  = *(const f32x4*)(bn_g + layer * C + cb);
        const f32x4 be = *(const f32x4*)(bn_b + layer * C + cb);
        const f32x4 m  = *(const f32x4*)(bn_m + layer * C + cb);
        const f32x4 v  = *(const f32x4*)(bn_v + layer * C + cb);
#pragma unroll
        for (int j = 0; j < 4; ++j) { sc[j] = g[j] / sqrtf(v[j] + 1e-5f); sh[j] = be[j] - m[j] * sc[j]; }
    } else {
#pragma unroll
        for (int j = 0; j < 4; ++j) { sc[j] = 1.f; sh[j] = 0.f; }
    }
#pragma unroll
    for (int r = 0; r < 4; ++r) {
        const int h = h0 + r;
        float* dst = F + (unsigned)(((d * HH + h) * WW + l15) * C + (lane >> 4) * 4);
        f32x4 val;
#pragma unroll
        for (int j = 0; j < 4; ++j) val[j] = acc[r][j] * sc[j] + sh[j];
        if (ACCUM) {
            const f32x4 old = *(const f32x4*)dst;
#pragma unroll
            for (int j = 0; j < 4; ++j) val[j] += old[j];
        }
        *(f32x4*)dst = val;
    }
}

// ---------------------------------------------------------------------------
__global__ __launch_bounds__(256)
void pack_x(const float* __restrict__ x, short* __restrict__ xp)
{
    const int b  = blockIdx.x;
    const int dp = b / HP_, hp = b % HP_;
    const int t  = threadIdx.x;
    const int d  = dp - 3, h = hp - 3;
    const bool inr = ((unsigned)d < (unsigned)DD) && ((unsigned)h < (unsigned)HH);
    short* row = xp + (unsigned)(dp * PLANEE + hp * ROWE);

    const int w = t & 15, ci = t >> 4;
    float v = 0.f;
    if (inr) v = x[ci * SP + d * HW + h * WW + w];
    __hip_bfloat16 hv = __float2bfloat16(v);
    row[(w + 2) * C + ci] = *(short*)&hv;
    if (t < 64) {
        const int pi = t >> 4;
        const int wp = (pi < 2) ? pi : (16 + pi);
        row[wp * C + (t & 15)] = 0;
    }
}

template <bool RELU, bool ADD>
__global__ __launch_bounds__(256)
void pack_f(float* __restrict__ S, const float* __restrict__ A2,
            short* __restrict__ P)
{
    const int b  = blockIdx.x;
    const int dp = b / HP_, hp = b % HP_;
    const int t  = threadIdx.x;
    const int d  = dp - 3, h = hp - 3;
    const bool inr = ((unsigned)d < (unsigned)DD) && ((unsigned)h < (unsigned)HH);
    short* row = P + (unsigned)(dp * PLANEE + hp * ROWE);

    const int ci = t & 15, w = t >> 4;
    float pv = 0.f;
    if (inr) {
        const unsigned idx = (unsigned)(((d * HH + h) * WW + w) * C + ci);
        const float v = S[idx];
        pv = RELU ? fmaxf(v, 0.f) : v;
        if (ADD) S[idx] = v + A2[idx];
    }
    __hip_bfloat16 hv = __float2bfloat16(pv);
    row[(w + 2) * C + ci] = *(short*)&hv;
    if (t < 64) {
        const int pi = t >> 4;
        const int wp = (pi < 2) ? pi : (16 + pi);
        row[wp * C + (t & 15)] = 0;
    }
}

// ---------------------------------------------------------------------------
// One launch packs all 11 weight tensors. Metadata baked in; block b -> weight
// via prefix table. style 0 = linear tap-pairs, style 1 = kw-pairs.
// ---------------------------------------------------------------------------
struct WSrcs { const float* p[11]; };

__global__ __launch_bounds__(256)
void pack_all(WSrcs ws, short* __restrict__ dst)
{
    constexpr int NW = 11;
    constexpr int style[NW] = {0, 0, 1,  1,   0, 1,  1,   0, 0, 1,  1};
    constexpr int khw[NW]   = {9, 9, 75, 245, 9, 75, 245, 1, 9, 75, 245};
    constexpr int kws[NW]   = {1, 1, 3,  5,   1, 3,  5,   1, 1, 3,  5};
    constexpr int pref[NW + 1] = {0, 5, 10, 60, 207, 212, 262, 409, 410, 415, 465, 612};

    const int b = blockIdx.x;
    int i = 0;
    while (i + 1 < NW + 1 && b >= pref[i + 1]) ++i;
    const int pl = b - pref[i];           // local pair index
    const float* src = ws.p[i];
    const int KHW = khw[i], KW = kws[i], KWP = (KW + 1) / 2;

    const int t  = threadIdx.x;
    const int l  = t >> 2, jj = t & 3;
    const int co = l & 15, cih = (l >> 4) & 1, tp = l >> 5;

    unsigned out = 0;
    if (style[i] == 0) {
        const int tap = 2 * pl + tp;
#pragma unroll
        for (int s = 0; s < 2; ++s) {
            const int ci = cih * 8 + jj * 2 + s;
            const float v = (tap < KHW) ? src[(co * C + ci) * KHW + tap] : 0.f;
            __hip_bfloat16 hv = __float2bfloat16(v);
            out |= ((unsigned)*(unsigned short*)&hv) << (16 * s);
        }
    } else {
        const int row = pl / KWP, kwp = pl % KWP;
        const int kw  = 2 * kwp + tp;
#pragma unroll
        for (int s = 0; s < 2; ++s) {
            const int ci = cih * 8 + jj * 2 + s;
            const float v = (kw < KW) ? src[(co * C + ci) * KHW + row * KW + kw] : 0.f;
            __hip_bfloat16 hv = __float2bfloat16(v);
            out |= ((unsigned)*(unsigned short*)&hv) << (16 * s);
        }
    }
    ((unsigned*)dst)[b * 256 + l * 4 + jj] = out;
}

// ---------------------------------------------------------------------------
__global__ __launch_bounds__(256)
void final_tr(const float* __restrict__ F, float* __restrict__ out)
{
    __shared__ float lds[16 * 17];
    const int b = blockIdx.x;
    const int d = b >> 3, hb = b & 7;
    const int t = threadIdx.x;
    for (int hh = 0; hh < 16; ++hh) {
        const int h = hb * 16 + hh;
        {
            const int ci = t & 15, w = t >> 4;
            const float v = F[(unsigned)(((d * HH + h) * WW + w) * C + ci)];
            lds[w * 17 + ci] = fmaxf(v, 0.f);
        }
        __syncthreads();
        {
            const int w = t & 15, co = t >> 4;
            out[(unsigned)(co * SP + d * HW + h * WW + w)] = lds[w * 17 + co];
        }
        __syncthreads();
    }
}

// ---------------------------------------------------------------------------
extern "C" void kernel_launch(void* const* d_in, const int* in_sizes, int n_in,
                              void* d_out, int out_size, void* d_ws, size_t ws_size,
                              hipStream_t stream)
{
    const float* x   = (const float*)d_in[0];
    const float* bng = (const float*)d_in[12];
    const float* bnb = (const float*)d_in[13];
    const float* bnm = (const float*)d_in[14];
    const float* bnv = (const float*)d_in[15];

    WSrcs ws;
    for (int i = 0; i < 11; ++i) ws.p[i] = (const float*)d_in[1 + i];

    short* XP  = (short*)d_ws;
    short* P2  = XP + PADE;
    float* F1  = (float*)(P2 + PADE);
    short* WPK = (short*)(F1 + TOT);
    float* F2  = (float*)d_out;           // fp32 scratch; fully rewritten at end

    // pair prefix (must match pack_all): pairs per weight
    const int pref[12] = {0, 5, 10, 60, 207, 212, 262, 409, 410, 415, 465, 612};
    int woff[11];
    for (int i = 0; i < 11; ++i) woff[i] = pref[i] * 512;   // shorts

    const dim3 blk(256);
    const dim3 pgrid(DP_ * HP_);            // 17956
    const dim3 sgrid(DD * 8);               // 1024 (small convs, final_tr)
    const dim3 tgrid((DD / 2) * 8);         // 512  (LDS tile convs)

    pack_all<<<dim3(612), blk, 0, stream>>>(ws, WPK);
    pack_x<<<pgrid, blk, 0, stream>>>(x, XP);

    // x1 = cbn(x, w1, 0) -> F1
    conv_mfma<3,3,1,9,false,true><<<sgrid, blk, 0, stream>>>(XP, WPK + woff[0], bng, bnb, bnm, bnv, 0, F1);
    pack_f<false,false><<<pgrid, blk, 0, stream>>>(F1, nullptr, P2);
    // F2 = x2 + x3 + x4
    conv_mfma<3,3,1,9,false,true><<<sgrid, blk, 0, stream>>>(P2, WPK + woff[1], bng, bnb, bnm, bnv, 1, F2);
    conv_tile_lds<5,5,3,true,true><<<tgrid, blk, 0, stream>>>(P2, WPK + woff[2], bng, bnb, bnm, bnv, 2, F2);
    conv_tile_lds<7,7,5,true,true><<<tgrid, blk, 0, stream>>>(P2, WPK + woff[3], bng, bnb, bnm, bnv, 3, F2);
    // t1p = relu(F2); F2 += F1
    pack_f<true,true><<<pgrid, blk, 0, stream>>>(F2, F1, P2);
    // F2 += x5 + x6 + x7
    conv_mfma<3,3,1,9,true,true><<<sgrid, blk, 0, stream>>>(P2, WPK + woff[4], bng, bnb, bnm, bnv, 4, F2);
    conv_tile_lds<5,5,3,true,true><<<tgrid, blk, 0, stream>>>(P2, WPK + woff[5], bng, bnb, bnm, bnv, 5, F2);
    conv_tile_lds<7,7,5,true,true><<<tgrid, blk, 0, stream>>>(P2, WPK + woff[6], bng, bnb, bnm, bnv, 6, F2);
    // xsp = relu(F2)
    pack_f<true,false><<<pgrid, blk, 0, stream>>>(F2, nullptr, P2);
    // F1 += y0 (1x1x1, no BN)
    conv_mfma<1,1,1,1,true,false><<<sgrid, blk, 0, stream>>>(P2, WPK + woff[7], bng, bnb, bnm, bnv, 0, F1);
    // F1 += y1, y2, y3
    conv_mfma<3,3,1,9,true,true><<<sgrid, blk, 0, stream>>>(XP, WPK + woff[8], bng, bnb, bnm, bnv, 7, F1);
    conv_tile_lds<5,5,3,true,true><<<tgrid, blk, 0, stream>>>(XP, WPK + woff[9], bng, bnb, bnm, bnv, 8, F1);
    conv_tile_lds<7,7,5,true,true><<<tgrid, blk, 0, stream>>>(XP, WPK + woff[10], bng, bnb, bnm, bnv, 9, F1);
    // out = relu(F1) transposed to [co][d][h][w]
    final_tr<<<sgrid, blk, 0, stream>>>(F1, (float*)d_out);

    (void)in_sizes; (void)n_in; (void)out_size; (void)ws_size;
}